// Round 4
// baseline (46.911 us; speedup 1.0000x reference)
//
#include <hip/hip_runtime.h>
#include <hip/hip_bf16.h>
#include <math.h>

#define NUM_ENTITY 100000
#define NUM_TYPE   5000
#define DIM        128
#define BATCH      512
#define MARGIN     2.0f

#define BT 32    // batch-tile rows per block
#define TT 32    // type-tile cols per block
#define DC 32    // d-chunk staged in LDS per iteration
#define LSTRIDE 36  // padded LDS row stride in floats (16B-aligned, rows stride 4 mod 32 banks)

// One wave per block. Round 3 showed grid starvation: 632x4-wave blocks =
// 2.47 blocks/CU -> 13.5% occupancy, VALUBusy 42%. 2512 one-wave blocks
// give ~9.8 waves/CU with near-free barriers; per-thread 4x4 tile keeps
// LDS traffic at 1.0 B/lane-op. No VGPR cap (rounds 1-2: caps spill).
__global__ __launch_bounds__(64) void l1dist_sigmoid_kernel(
    const float* __restrict__ ent,
    const float* __restrict__ typ,
    const int*   __restrict__ xb,
    float*       __restrict__ out)
{
    __shared__ float eT[BT * LSTRIDE];
    __shared__ float tT[TT * LSTRIDE];

    const int tid = threadIdx.x;   // 0..63
    const int tx  = tid & 7;       // type-dir thread coord (8)
    const int ty  = tid >> 3;      // batch-dir thread coord (8)
    const int b0  = blockIdx.y * BT;
    const int t0  = blockIdx.x * TT;

    // staging: 32 rows x 32 floats = 256 float4 per tile; 64 threads ->
    // 4 float4 each per tile per chunk. slot s covers row ty+8s, cols tx*4..+3
    const int cc = tx << 2;
    int e_row[4], t_row[4];
#pragma unroll
    for (int s = 0; s < 4; ++s) {
        e_row[s] = xb[b0 + ty + 8 * s];
        t_row[s] = min(t0 + ty + 8 * s, NUM_TYPE - 1);
    }

    float acc[4][4];
#pragma unroll
    for (int i = 0; i < 4; ++i)
#pragma unroll
        for (int j = 0; j < 4; ++j) acc[i][j] = 0.0f;

    for (int dc = 0; dc < DIM; dc += DC) {
        __syncthreads();   // protect LDS from previous chunk's readers
#pragma unroll
        for (int s = 0; s < 4; ++s)
            *(float4*)&eT[(ty + 8 * s) * LSTRIDE + cc] =
                *(const float4*)&ent[e_row[s] * DIM + dc + cc];
#pragma unroll
        for (int s = 0; s < 4; ++s)
            *(float4*)&tT[(ty + 8 * s) * LSTRIDE + cc] =
                *(const float4*)&typ[t_row[s] * DIM + dc + cc];
        __syncthreads();

#pragma unroll
        for (int k = 0; k < DC; k += 4) {
            float4 ev[4], tv[4];
#pragma unroll
            for (int i = 0; i < 4; ++i)
                ev[i] = *(const float4*)&eT[(ty + 8 * i) * LSTRIDE + k];
#pragma unroll
            for (int j = 0; j < 4; ++j)
                tv[j] = *(const float4*)&tT[(tx + 8 * j) * LSTRIDE + k];
#pragma unroll
            for (int i = 0; i < 4; ++i)
#pragma unroll
                for (int j = 0; j < 4; ++j) {
                    acc[i][j] += fabsf(ev[i].x - tv[j].x);
                    acc[i][j] += fabsf(ev[i].y - tv[j].y);
                    acc[i][j] += fabsf(ev[i].z - tv[j].z);
                    acc[i][j] += fabsf(ev[i].w - tv[j].w);
                }
        }
    }

    // epilogue: sigmoid(MARGIN - dist), guarded store on t
#pragma unroll
    for (int i = 0; i < 4; ++i) {
        const int b = b0 + ty + 8 * i;
#pragma unroll
        for (int j = 0; j < 4; ++j) {
            const int t = t0 + tx + 8 * j;
            if (t < NUM_TYPE) {
                const float x = MARGIN - acc[i][j];
                out[b * NUM_TYPE + t] = 1.0f / (1.0f + __expf(-x));
            }
        }
    }
}

extern "C" void kernel_launch(void* const* d_in, const int* in_sizes, int n_in,
                              void* d_out, int out_size, void* d_ws, size_t ws_size,
                              hipStream_t stream) {
    const float* ent = (const float*)d_in[0];
    const float* typ = (const float*)d_in[1];
    const int*   xb  = (const int*)d_in[2];
    float*       out = (float*)d_out;

    dim3 grid((NUM_TYPE + TT - 1) / TT, BATCH / BT);  // (157, 16) = 2512 blocks
    dim3 block(64);
    l1dist_sigmoid_kernel<<<grid, block, 0, stream>>>(ent, typ, xb, out);
}